// Round 9
// baseline (1147.952 us; speedup 1.0000x reference)
//
#include <hip/hip_runtime.h>
#include <hip/hip_bf16.h>

#define N_ 1024
#define M_ 1152
#define L_ 32
#define NATSTRIDE (L_*M_)   // 36864
#define CONVK 129
#define OUTW 1024
#define NSTEP 31

typedef __attribute__((ext_vector_type(8))) short short8;
typedef __attribute__((ext_vector_type(4))) float f32x4;
typedef unsigned long long u64;

__device__ __forceinline__ unsigned short f2bf(float f) {
    unsigned int u = __float_as_uint(f);
    u += 0x7FFFu + ((u >> 16) & 1u);   // round-to-nearest-even
    return (unsigned short)(u >> 16);
}
__device__ __forceinline__ float bf2f(unsigned short b) {
    return __uint_as_float(((unsigned int)b) << 16);
}

// Split convW[m][k][2] -> w0t[m][k], w1t[m][k] (bf16, k-contiguous = B^T layout)
__global__ __launch_bounds__(256) void build_wsplit(const float* __restrict__ convW,
                                                    unsigned short* __restrict__ w0t,
                                                    unsigned short* __restrict__ w1t) {
    int idx = blockIdx.x * blockDim.x + threadIdx.x;
    if (idx >= M_ * M_) return;
    int m = idx / M_;
    int k = idx - m * M_;
    const float* s = convW + (size_t)m * (2 * M_) + 2 * k;
    w0t[idx] = f2bf(s[0]);
    w1t[idx] = f2bf(s[1]);
}

// h0 = bf16(NATree[:, L-1, :])
__global__ __launch_bounds__(256) void build_h0(const float* __restrict__ nat,
                                                unsigned short* __restrict__ h0) {
    int idx = blockIdx.x * blockDim.x + threadIdx.x;
    if (idx >= N_ * M_) return;
    int n = idx / M_;
    int m = idx - n * M_;
    h0[idx] = f2bf(nat[(size_t)n * NATSTRIDE + (size_t)(L_ - 1) * M_ + m]);
}

// rbf[t][n][m] = bf16(NATree[n][30-t][m])  for t = 0..30
__global__ __launch_bounds__(256) void build_rbf(const float* __restrict__ nat,
                                                 unsigned short* __restrict__ rbf) {
    int idx = blockIdx.x * blockDim.x + threadIdx.x;   // one thread per 8 elems
    if (idx >= NSTEP * N_ * M_ / 8) return;
    int o = idx * 8;
    int t = o / (N_ * M_);
    int rem = o - t * (N_ * M_);
    int n = rem / M_;
    int m = rem - n * M_;
    int l = (NSTEP - 1) - t;
    const float* s = nat + (size_t)n * NATSTRIDE + (size_t)l * M_ + m;
    f32x4 v0 = *(const f32x4*)(s);
    f32x4 v1 = *(const f32x4*)(s + 4);
    short8 tt;
    #pragma unroll
    for (int e = 0; e < 4; ++e) {
        tt[e]     = (short)f2bf(v0[e]);
        tt[4 + e] = (short)f2bf(v1[e]);
    }
    *(short8*)(rbf + o) = tt;
}

// ---------------- Phase 1: Rpre = bf16( r_t @ W0^T + b ) for all t (unchanged) ----------------
#define P_BM 128
#define P_BN 128
#define P_BK 64
#define P_NT (M_ / P_BK)    // 18
#define P_LDP 72

__global__ __launch_bounds__(256) void rpre_gemm(
    const unsigned short* __restrict__ rbf,
    const unsigned short* __restrict__ w0t,
    const float* __restrict__ convb,
    unsigned short* __restrict__ rpre)
{
    __shared__ __align__(16) unsigned short As[2][P_BM * P_LDP];
    __shared__ __align__(16) unsigned short Bs[2][P_BN * P_LDP];

    int tid = threadIdx.x;
    int lane = tid & 63;
    int w = tid >> 6;
    int wr = w >> 1, wc = w & 1;
    int raw = blockIdx.y * 9 + blockIdx.x;
    int logical = (raw & 7) * 279 + (raw >> 3);   // 2232 = 8*279 bijective chunked swizzle
    int bx = logical % 9, by = logical / 9;
    int n0 = by * P_BM;
    int m0 = bx * P_BN;

    int lr = lane & 15;
    int lk = (lane >> 4) * 8;
    int srow = tid >> 3;
    int skcol = (tid & 7) * 8;

    f32x4 acc[4][4] = {};

    auto loadTile = [&](int it, short8 a[4], short8 b[4]) {
        int kb = it * P_BK;
        #pragma unroll
        for (int i = 0; i < 4; ++i) {
            int row = srow + i * 32;
            a[i] = *(const short8*)(rbf + (size_t)(n0 + row) * M_ + kb + skcol);
            b[i] = *(const short8*)(w0t + (size_t)(m0 + row) * M_ + kb + skcol);
        }
    };
    auto writeTile = [&](int buf, short8 a[4], short8 b[4]) {
        #pragma unroll
        for (int i = 0; i < 4; ++i) {
            *(short8*)&As[buf][(srow + i * 32) * P_LDP + skcol] = a[i];
            *(short8*)&Bs[buf][(srow + i * 32) * P_LDP + skcol] = b[i];
        }
    };

    {
        short8 a0[4], b0[4];
        loadTile(0, a0, b0);
        writeTile(0, a0, b0);
    }
    __syncthreads();

    int cur = 0;
    for (int it = 0; it < P_NT; ++it) {
        short8 a2[4], b2[4];
        if (it + 1 < P_NT) loadTile(it + 1, a2, b2);

        #pragma unroll
        for (int ks = 0; ks < P_BK; ks += 32) {
            short8 af[4], bf_[4];
            #pragma unroll
            for (int mi = 0; mi < 4; ++mi)
                af[mi] = *(const short8*)&As[cur][(wr * 64 + mi * 16 + lr) * P_LDP + ks + lk];
            #pragma unroll
            for (int ni = 0; ni < 4; ++ni)
                bf_[ni] = *(const short8*)&Bs[cur][(wc * 64 + ni * 16 + lr) * P_LDP + ks + lk];
            #pragma unroll
            for (int mi = 0; mi < 4; ++mi)
                #pragma unroll
                for (int ni = 0; ni < 4; ++ni)
                    acc[mi][ni] = __builtin_amdgcn_mfma_f32_16x16x32_bf16(
                        af[mi], bf_[ni], acc[mi][ni], 0, 0, 0);
        }
        if (it + 1 < P_NT) {
            writeTile(cur ^ 1, a2, b2);
            __syncthreads();
            cur ^= 1;
        }
    }

    #pragma unroll
    for (int mi = 0; mi < 4; ++mi) {
        #pragma unroll
        for (int ni = 0; ni < 4; ++ni) {
            int mloc = m0 + wc * 64 + ni * 16 + lr;
            float bias = convb[mloc];
            #pragma unroll
            for (int j = 0; j < 4; ++j) {
                int g = n0 + wr * 64 + mi * 16 + (lane >> 4) * 4 + j;
                rpre[(size_t)g * M_ + mloc] = f2bf(acc[mi][ni][j] + bias);
            }
        }
    }
}

// ---------------- Phase 3: persistent chain v4 ----------------
// 144 blocks = 16 rowgrps (64 rows) x 9 colgrps (128 cols); 145 KiB LDS, 1 block/CU,
// all 144 co-resident (<=256 CUs) -> rowgroup barrier is deadlock-free.
// Per step: stage FULL h row-panel (64 x 1152) into LDS once (batched agent loads),
// then a barrier-free 36-iter K-loop: A frags ds_read (immediate offsets), B frags
// direct from L2-resident w1t with depth-3 register prefetch. h exchange stays
// agent-scope (mapping-agnostic coherence); barrier = padded relaxed counters.
#define C_LDP 1160          // padded row stride in elems (2320 B)
#define N_RG 16
#define N_CG 9

__global__ __launch_bounds__(256) void chain_kernel(
    const unsigned short* __restrict__ w1t,
    const unsigned short* __restrict__ rpre,
    const unsigned short* __restrict__ rbf,
    const float* __restrict__ x,
    unsigned short* h0buf,                  // holds h_0 on entry (parity 0)
    unsigned short* h1buf,                  // parity 1
    float* __restrict__ res,
    unsigned int* bar)                      // 16 counters, 128B apart, zeroed per launch
{
    __shared__ __align__(16) unsigned short As[64 * C_LDP];   // 145 KiB

    int tid = threadIdx.x;
    int lane = tid & 63;
    int w = tid >> 6;
    int wr = w >> 1, wc = w & 1;            // wave tile: 32 rows x 64 cols
    int bid = blockIdx.x;
    int rg = bid & 15;
    int cg = bid >> 4;
    int n0 = rg * 64;
    int m0 = cg * 128;
    int lr = lane & 15;
    int lg = lane >> 4;

    // A-stage mapping: thread -> row (tid>>2), quarter q (tid&3); 36 16B chunks per thread
    int arow = tid >> 2;
    int aq = tid & 3;

    // B fragment base pointers (constant across steps)
    const unsigned short* bbase[4];
    #pragma unroll
    for (int ni = 0; ni < 4; ++ni)
        bbase[ni] = w1t + (size_t)(m0 + wc * 64 + ni * 16 + lr) * M_ + lg * 8;

    // A fragment base pointers into LDS
    const unsigned short* a0p = &As[(wr * 32 + lr) * C_LDP + lg * 8];
    const unsigned short* a1p = a0p + 16 * C_LDP;

    for (int t = 0; t < NSTEP; ++t) {
        const unsigned short* hin  = (t & 1) ? h1buf : h0buf;
        unsigned short*       hout = (t & 1) ? h0buf : h1buf;
        const unsigned short* rpre_t = rpre + (size_t)t * N_ * M_;
        const unsigned short* rbf_t  = rbf  + (size_t)t * N_ * M_;
        int final_step = (t == NSTEP - 1);

        // ---- stage full h panel into LDS: 3 batches x 12 chunks (agent loads, deep in flight)
        {
            const unsigned short* hrow = hin + (size_t)(n0 + arow) * M_;
            unsigned short* lrow = &As[arow * C_LDP];
            #pragma unroll
            for (int b = 0; b < 3; ++b) {
                u64 tmp[24];
                #pragma unroll
                for (int j = 0; j < 12; ++j) {
                    int c = aq + (b * 12 + j) * 4;          // chunk 0..143
                    const unsigned short* p = hrow + c * 8;
                    tmp[2 * j]     = __hip_atomic_load((const u64*)p,       __ATOMIC_RELAXED, __HIP_MEMORY_SCOPE_AGENT);
                    tmp[2 * j + 1] = __hip_atomic_load((const u64*)(p + 4), __ATOMIC_RELAXED, __HIP_MEMORY_SCOPE_AGENT);
                }
                #pragma unroll
                for (int j = 0; j < 12; ++j) {
                    int c = aq + (b * 12 + j) * 4;
                    union { u64 q[2]; short8 v; } u;
                    u.q[0] = tmp[2 * j];
                    u.q[1] = tmp[2 * j + 1];
                    *(short8*)(lrow + c * 8) = u.v;
                }
            }
        }

        // ---- prefetch epilogue operands (plain cached; latency hides under K-loop)
        unsigned short preR[2][4][4], rbfR[2][4][4];
        #pragma unroll
        for (int mi = 0; mi < 2; ++mi)
            #pragma unroll
            for (int ni = 0; ni < 4; ++ni) {
                int mloc = m0 + wc * 64 + ni * 16 + lr;
                #pragma unroll
                for (int j = 0; j < 4; ++j) {
                    int nloc = n0 + wr * 32 + mi * 16 + lg * 4 + j;
                    preR[mi][ni][j] = rpre_t[(size_t)nloc * M_ + mloc];
                    rbfR[mi][ni][j] = rbf_t[(size_t)nloc * M_ + mloc];
                }
            }

        __syncthreads();   // A panel ready

        // ---- barrier-free K-loop: 36 iters, depth-3 B prefetch
        f32x4 acc[2][4] = {};
        short8 breg[3][4];
        #pragma unroll
        for (int d = 0; d < 3; ++d)
            #pragma unroll
            for (int ni = 0; ni < 4; ++ni)
                breg[d][ni] = *(const short8*)(bbase[ni] + d * 32);

        #pragma unroll
        for (int it = 0; it < 36; ++it) {
            short8 af0 = *(const short8*)(a0p + it * 32);
            short8 af1 = *(const short8*)(a1p + it * 32);
            int slot = it % 3;
            #pragma unroll
            for (int ni = 0; ni < 4; ++ni) {
                acc[0][ni] = __builtin_amdgcn_mfma_f32_16x16x32_bf16(af0, breg[slot][ni], acc[0][ni], 0, 0, 0);
                acc[1][ni] = __builtin_amdgcn_mfma_f32_16x16x32_bf16(af1, breg[slot][ni], acc[1][ni], 0, 0, 0);
            }
            if (it + 3 < 36) {
                #pragma unroll
                for (int ni = 0; ni < 4; ++ni)
                    breg[slot][ni] = *(const short8*)(bbase[ni] + (it + 3) * 32);
            }
        }

        __syncthreads();   // all waves done reading As before next step's restage

        // ---- epilogue
        #pragma unroll
        for (int mi = 0; mi < 2; ++mi) {
            #pragma unroll
            for (int ni = 0; ni < 4; ++ni) {
                int mloc = m0 + wc * 64 + ni * 16 + lr;
                #pragma unroll
                for (int j = 0; j < 4; ++j) {
                    int nloc = n0 + wr * 32 + mi * 16 + lg * 4 + j;
                    float pre = acc[mi][ni][j] + bf2f(preR[mi][ni][j]);
                    float hv = tanhf(pre) + bf2f(rbfR[mi][ni][j]);
                    if (final_step) {
                        res[(size_t)nloc * M_ + mloc] = tanhf(tanhf(hv) + x[(size_t)nloc * M_ + mloc]);
                    } else {
                        __hip_atomic_store(&hout[(size_t)nloc * M_ + mloc], f2bf(hv),
                                           __ATOMIC_RELAXED, __HIP_MEMORY_SCOPE_AGENT);
                    }
                }
            }
        }

        // ---- per-rowgroup barrier (fan-in 9), relaxed counters 128B apart
        if (!final_step) {
            __syncthreads();   // drains vmcnt(0) per wave -> h stores at coherence point
            if (tid == 0) {
                __hip_atomic_fetch_add(&bar[rg << 5], 1u,
                                       __ATOMIC_RELAXED, __HIP_MEMORY_SCOPE_AGENT);
                unsigned int target = (unsigned)N_CG * (unsigned)(t + 1);
                while (__hip_atomic_load(&bar[rg << 5], __ATOMIC_RELAXED,
                                         __HIP_MEMORY_SCOPE_AGENT) < target) {
                    __builtin_amdgcn_s_sleep(1);
                }
            }
            __syncthreads();
        }
    }
}

// out[n][j] = conv2b + sum_k res[n][j+k] * conv2W[k]
__global__ __launch_bounds__(256) void conv_out_kernel(
    const float* __restrict__ res, const float* __restrict__ w2,
    const float* __restrict__ b2, float* __restrict__ out)
{
    __shared__ float row[M_];
    __shared__ float wk[CONVK];
    int n = blockIdx.x;
    int tid = threadIdx.x;
    for (int i = tid; i < M_; i += 256) row[i] = res[(size_t)n * M_ + i];
    if (tid < CONVK) wk[tid] = w2[tid];
    __syncthreads();
    float b = b2[0];
    int j0 = tid * 4;
    float s0 = b, s1 = b, s2 = b, s3 = b;
    float r0 = row[j0], r1 = row[j0 + 1], r2 = row[j0 + 2], r3 = row[j0 + 3];
    for (int k = 0; k < CONVK; ++k) {
        float wv = wk[k];
        s0 += r0 * wv; s1 += r1 * wv; s2 += r2 * wv; s3 += r3 * wv;
        if (k < CONVK - 1) { r0 = r1; r1 = r2; r2 = r3; r3 = row[j0 + 4 + k]; }
    }
    float* o = out + (size_t)n * OUTW + j0;
    o[0] = s0; o[1] = s1; o[2] = s2; o[3] = s3;
}

extern "C" void kernel_launch(void* const* d_in, const int* in_sizes, int n_in,
                              void* d_out, int out_size, void* d_ws, size_t ws_size,
                              hipStream_t stream) {
    const float* NATree = (const float*)d_in[0];
    const float* x      = (const float*)d_in[1];
    const float* convW  = (const float*)d_in[2];
    const float* convb  = (const float*)d_in[3];
    const float* conv2W = (const float*)d_in[4];
    const float* conv2b = (const float*)d_in[5];
    float* out = (float*)d_out;

    char* ws = (char*)d_ws;
    size_t off = 0;
    auto alloc = [&](size_t bytes) {
        void* p = ws + off;
        off = (off + bytes + 255) & ~(size_t)255;
        return p;
    };
    unsigned short* w0t  = (unsigned short*)alloc((size_t)M_ * M_ * 2);
    unsigned short* w1t  = (unsigned short*)alloc((size_t)M_ * M_ * 2);
    unsigned short* hA   = (unsigned short*)alloc((size_t)N_ * M_ * 2);
    unsigned short* hB   = (unsigned short*)alloc((size_t)N_ * M_ * 2);
    unsigned short* rpre = (unsigned short*)alloc((size_t)NSTEP * N_ * M_ * 2);
    unsigned short* rbf  = (unsigned short*)alloc((size_t)NSTEP * N_ * M_ * 2);
    float*          res  = (float*)alloc((size_t)N_ * M_ * 4);
    unsigned int*   bar  = (unsigned int*)alloc(4096);

    hipMemsetAsync(bar, 0, 4096, stream);
    build_wsplit<<<(M_ * M_ + 255) / 256, 256, 0, stream>>>(convW, w0t, w1t);
    build_h0<<<(N_ * M_ + 255) / 256, 256, 0, stream>>>(NATree, hA);
    build_rbf<<<(NSTEP * N_ * M_ / 8 + 255) / 256, 256, 0, stream>>>(NATree, rbf);

    // Phase 1: all 31 r_t @ W0^T + b in one GEMM (M = 31744)
    rpre_gemm<<<dim3(M_ / P_BN, (NSTEP * N_) / P_BM), 256, 0, stream>>>(rbf, w0t, convb, rpre);

    // Phase 3: persistent chain v4 (144 blocks, 1/CU; barrier-free K-loop)
    chain_kernel<<<N_RG * N_CG, 256, 0, stream>>>(w1t, rpre, rbf, x, hA, hB, res, bar);

    conv_out_kernel<<<1024, 256, 0, stream>>>(res, conv2W, conv2b, out);
}